// Round 3
// baseline (51.122 us; speedup 1.0000x reference)
//
#include <hip/hip_runtime.h>

// 5-layer MLP 30->64->32->16->8->2 with ReLU, bf16 MFMA (16x16x32), batch tile N=16.
// FULLY REGISTER-RESIDENT: with k-slot map k = 4g + (i&3) + 16*(i>>2) and the
// m89-verified C/D layout m = 16t + 4g + q (same lane group g!), the B-fragment
// of layer L+1 is a lane-local repack of layer L's accumulator:
//   B[i] = bf16(relu( c[t = i>>2 (+2s)][q = i&3] ))
// -> no LDS, no cross-lane ops, no barriers anywhere in the main loop.
// A/B use the same slot->k map, so any HW slot permutation cancels in A x B.

typedef float        f32x4 __attribute__((ext_vector_type(4)));
typedef unsigned int u32x4 __attribute__((ext_vector_type(4)));
typedef short        s16x8 __attribute__((ext_vector_type(8)));

static __device__ __forceinline__ unsigned short f2bf(float f) {
    return __builtin_bit_cast(unsigned short, (__bf16)f);
}
static __device__ __forceinline__ unsigned int pkbf(float a, float b) {
    return (unsigned int)f2bf(a) | ((unsigned int)f2bf(b) << 16);
}
static __device__ __forceinline__ unsigned int rp2(float a, float b) {
    return pkbf(fmaxf(a, 0.0f), fmaxf(b, 0.0f));
}

#define MFMA(A, B, C) __builtin_amdgcn_mfma_f32_16x16x32_bf16((A), (B), (C), 0, 0, 0)

__global__ __launch_bounds__(256) void mlp_mfma_kernel(
    const float* __restrict__ x,
    const float* __restrict__ w1, const float* __restrict__ b1,
    const float* __restrict__ w2, const float* __restrict__ b2,
    const float* __restrict__ w3, const float* __restrict__ b3,
    const float* __restrict__ w4, const float* __restrict__ b4,
    const float* __restrict__ w5, const float* __restrict__ b5,
    float* __restrict__ out, int n)
{
    const int lane = threadIdx.x & 63;
    const int wv   = threadIdx.x >> 6;
    const int g    = lane >> 4;
    const int ml   = lane & 15;

    // ---------------- per-wave weight / bias fragment build ----------------
    s16x8 A1[4], A2[2][2], A3, A4, A5;
    #pragma unroll
    for (int t = 0; t < 4; ++t) {
        #pragma unroll
        for (int i = 0; i < 8; ++i) {
            const int k = 4*g + (i & 3) + ((i >> 2) << 4);
            const int m = 16*t + ml;
            float v = (k < 30) ? w1[m*30 + k] : ((k == 30) ? b1[m] : 0.0f);
            A1[t][i] = (short)f2bf(v);
        }
    }
    #pragma unroll
    for (int t = 0; t < 2; ++t)
        #pragma unroll
        for (int s = 0; s < 2; ++s)
            #pragma unroll
            for (int i = 0; i < 8; ++i) {
                const int k = 4*g + (i & 3) + ((i >> 2) << 4);
                A2[t][s][i] = (short)f2bf(w2[(16*t + ml)*64 + 32*s + k]);
            }
    #pragma unroll
    for (int i = 0; i < 8; ++i) {
        const int k = 4*g + (i & 3) + ((i >> 2) << 4);
        A3[i] = (short)f2bf(w3[ml*32 + k]);
        float v4 = 0.0f, v5 = 0.0f;
        if (ml < 8) v4 = (k < 16) ? w4[ml*16 + k] : ((k == 16) ? b4[ml] : 0.0f);
        if (ml < 2) v5 = (k <  8) ? w5[ml*8  + k] : ((k ==  8) ? b5[ml] : 0.0f);
        A4[i] = (short)f2bf(v4);
        A5[i] = (short)f2bf(v5);
    }
    f32x4 bias2[2], bias3;
    #pragma unroll
    for (int t = 0; t < 2; ++t)
        #pragma unroll
        for (int q = 0; q < 4; ++q)
            bias2[t][q] = b2[16*t + 4*g + q];
    #pragma unroll
    for (int q = 0; q < 4; ++q)
        bias3[q] = b3[4*g + q];

    // ---------------- batch-tile loop (grid-stride by wave) ----------------
    const int ntiles = (n + 15) >> 4;
    const int nwaves = gridDim.x * 4;
    int tile = blockIdx.x * 4 + wv;
    if (tile >= ntiles) return;

    auto loadx = [&](int t, f32x4& xa, f32x4& xb) {
        int row = t*16 + ml;
        if (row >= n) row = n - 1;
        const float* rp = x + (size_t)row * 30;     // rows are 8B-aligned
        float2 a01 = *(const float2*)(rp + 4*g);
        float2 a23 = *(const float2*)(rp + 4*g + 2);
        xa[0] = a01.x; xa[1] = a01.y; xa[2] = a23.x; xa[3] = a23.y;
        if (g < 3) {
            float2 b01 = *(const float2*)(rp + 16 + 4*g);
            float2 b23 = *(const float2*)(rp + 18 + 4*g);
            xb[0] = b01.x; xb[1] = b01.y; xb[2] = b23.x; xb[3] = b23.y;
        } else {
            float2 b01 = *(const float2*)(rp + 28);
            xb[0] = b01.x; xb[1] = b01.y;
            xb[2] = 1.0f;   // k==30 slot multiplies the b1 column of W1
            xb[3] = 0.0f;   // k==31 pad
        }
    };

    f32x4 xa, xb;
    loadx(tile, xa, xb);

    const f32x4 zero = {0.0f, 0.0f, 0.0f, 0.0f};

    while (true) {
        const int nt = tile + nwaves;
        const bool have_next = (nt < ntiles);
        f32x4 nxa, nxb;
        if (have_next) loadx(nt, nxa, nxb);   // prefetch next tile's x

        // ---- layer 1: 30(+bias)->64 ----
        u32x4 u0;
        u0.x = pkbf(xa[0], xa[1]); u0.y = pkbf(xa[2], xa[3]);
        u0.z = pkbf(xb[0], xb[1]); u0.w = pkbf(xb[2], xb[3]);
        s16x8 B0 = __builtin_bit_cast(s16x8, u0);
        f32x4 c1[4];
        #pragma unroll
        for (int t = 0; t < 4; ++t) c1[t] = MFMA(A1[t], B0, zero);

        // ---- layer 2: 64->32 (K = 2 steps), B from registers ----
        s16x8 B1[2];
        #pragma unroll
        for (int s = 0; s < 2; ++s) {
            u32x4 u;
            u.x = rp2(c1[2*s][0],     c1[2*s][1]);
            u.y = rp2(c1[2*s][2],     c1[2*s][3]);
            u.z = rp2(c1[2*s + 1][0], c1[2*s + 1][1]);
            u.w = rp2(c1[2*s + 1][2], c1[2*s + 1][3]);
            B1[s] = __builtin_bit_cast(s16x8, u);
        }
        f32x4 c2[2];
        #pragma unroll
        for (int t = 0; t < 2; ++t) {
            f32x4 a = bias2[t];
            #pragma unroll
            for (int s = 0; s < 2; ++s) a = MFMA(A2[t][s], B1[s], a);
            c2[t] = a;
        }

        // ---- layer 3: 32->16, B from registers ----
        u32x4 u2;
        u2.x = rp2(c2[0][0], c2[0][1]);
        u2.y = rp2(c2[0][2], c2[0][3]);
        u2.z = rp2(c2[1][0], c2[1][1]);
        u2.w = rp2(c2[1][2], c2[1][3]);
        f32x4 c3 = MFMA(A3, __builtin_bit_cast(s16x8, u2), bias3);

        // ---- layer 4: 16(+bias)->8, B from registers ----
        u32x4 u3;
        u3.x = rp2(c3[0], c3[1]);
        u3.y = rp2(c3[2], c3[3]);
        u3.z = (g == 0) ? 0x3F80u : 0u;   // k==16 slot = 1.0 (bias), rest 0
        u3.w = 0u;
        f32x4 c4 = MFMA(A4, __builtin_bit_cast(s16x8, u3), zero);

        // ---- layer 5: 8(+bias)->2 (no ReLU), B from registers ----
        // c4 == 0 exactly for g >= 2 (A4 rows m>=8 are zero), so rp2 gives 0.
        u32x4 u4;
        u4.x = (g == 2) ? 0x3F80u : rp2(c4[0], c4[1]);  // k==8 slot = 1.0 (bias)
        u4.y = (g == 2) ? 0u      : rp2(c4[2], c4[3]);
        u4.z = 0u; u4.w = 0u;
        f32x4 c5 = MFMA(A5, __builtin_bit_cast(s16x8, u4), zero);

        const int orow = tile*16 + lane;   // lanes 0..15: m=0 -> c5[0], m=1 -> c5[1]
        if (lane < 16 && orow < n) {
            float2 o; o.x = c5[0]; o.y = c5[1];
            *(float2*)(out + (size_t)orow * 2) = o;
        }

        if (!have_next) break;
        xa = nxa; xb = nxb; tile = nt;
    }
}

extern "C" void kernel_launch(void* const* d_in, const int* in_sizes, int n_in,
                              void* d_out, int out_size, void* d_ws, size_t ws_size,
                              hipStream_t stream) {
    const float* x  = (const float*)d_in[0];
    const float* w1 = (const float*)d_in[1];
    const float* b1 = (const float*)d_in[2];
    const float* w2 = (const float*)d_in[3];
    const float* b2 = (const float*)d_in[4];
    const float* w3 = (const float*)d_in[5];
    const float* b3 = (const float*)d_in[6];
    const float* w4 = (const float*)d_in[7];
    const float* b4 = (const float*)d_in[8];
    const float* w5 = (const float*)d_in[9];
    const float* b5 = (const float*)d_in[10];
    float* out = (float*)d_out;

    const int n = in_sizes[0] / 30;           // 1,000,000 rows
    const int ntiles = (n + 15) >> 4;         // 62,500
    int blocks = (ntiles + 3) / 4;
    if (blocks > 2048) blocks = 2048;         // 8192 waves, ~7.6 tiles/wave

    mlp_mfma_kernel<<<blocks, 256, 0, stream>>>(
        x, w1, b1, w2, b2, w3, b3, w4, b4, w5, b5, out, n);
}

// Round 4
// 49.304 us; speedup vs baseline: 1.0369x; 1.0369x over previous
//
#include <hip/hip_runtime.h>

// 5-layer MLP 30->64->32->16->8->2 with ReLU, bf16 MFMA (16x16x32), batch tile N=16.
// Register-resident layer chain (k-slot map k = 4g+(i&3)+16*(i>>2); C/D layout
// m = 16t+4g+q, same lane group -> inter-layer repack is lane-local).
// Round-4 changes vs round 3:
//  (1) 2-tile ILP: each wave runs TWO independent tile chains, stage-interleaved.
//  (2) Weights staged once per block into LDS (coalesced), fragments built from
//      LDS -> no per-wave scattered global weight loads.

typedef float        f32x4 __attribute__((ext_vector_type(4)));
typedef unsigned int u32x4 __attribute__((ext_vector_type(4)));
typedef short        s16x8 __attribute__((ext_vector_type(8)));

static __device__ __forceinline__ unsigned short f2bf(float f) {
    return __builtin_bit_cast(unsigned short, (__bf16)f);
}
static __device__ __forceinline__ unsigned int pkbf(float a, float b) {
    return (unsigned int)f2bf(a) | ((unsigned int)f2bf(b) << 16);
}
static __device__ __forceinline__ unsigned int rp2(float a, float b) {
    return pkbf(fmaxf(a, 0.0f), fmaxf(b, 0.0f));
}

#define MFMA(A, B, C) __builtin_amdgcn_mfma_f32_16x16x32_bf16((A), (B), (C), 0, 0, 0)

// LDS weight-cache layout (float offsets)
#define OW1 0
#define OW2 1920
#define OW3 3968
#define OW4 4480
#define OW5 4608
#define OB1 4624
#define OB2 4688
#define OB3 4720
#define OB4 4736
#define OB5 4744
#define WTOT 4746

__global__ __launch_bounds__(256) void mlp_mfma_kernel(
    const float* __restrict__ x,
    const float* __restrict__ w1, const float* __restrict__ b1,
    const float* __restrict__ w2, const float* __restrict__ b2,
    const float* __restrict__ w3, const float* __restrict__ b3,
    const float* __restrict__ w4, const float* __restrict__ b4,
    const float* __restrict__ w5, const float* __restrict__ b5,
    float* __restrict__ out, int n)
{
    __shared__ float W[WTOT];

    const int tid  = threadIdx.x;
    const int lane = tid & 63;
    const int wv   = tid >> 6;
    const int g    = lane >> 4;
    const int ml   = lane & 15;

    // ---- stage raw weights into LDS, coalesced, once per block ----
    for (int i = tid; i < 1920; i += 256) W[OW1 + i] = w1[i];
    for (int i = tid; i < 2048; i += 256) W[OW2 + i] = w2[i];
    for (int i = tid; i < 512;  i += 256) W[OW3 + i] = w3[i];
    if (tid < 128) W[OW4 + tid] = w4[tid];
    if (tid < 16)  W[OW5 + tid] = w5[tid];
    if (tid < 64)  W[OB1 + tid] = b1[tid];
    if (tid < 32)  W[OB2 + tid] = b2[tid];
    if (tid < 16)  W[OB3 + tid] = b3[tid];
    if (tid < 8)   W[OB4 + tid] = b4[tid];
    if (tid < 2)   W[OB5 + tid] = b5[tid];
    __syncthreads();

    // ---- per-wave weight / bias fragment build (from LDS) ----
    s16x8 A1[4], A2[2][2], A3, A4, A5;
    #pragma unroll
    for (int t = 0; t < 4; ++t) {
        #pragma unroll
        for (int i = 0; i < 8; ++i) {
            const int k = 4*g + (i & 3) + ((i >> 2) << 4);
            const int m = 16*t + ml;
            float v = (k < 30) ? W[OW1 + m*30 + k] : ((k == 30) ? W[OB1 + m] : 0.0f);
            A1[t][i] = (short)f2bf(v);
        }
    }
    #pragma unroll
    for (int t = 0; t < 2; ++t)
        #pragma unroll
        for (int s = 0; s < 2; ++s)
            #pragma unroll
            for (int i = 0; i < 8; ++i) {
                const int k = 4*g + (i & 3) + ((i >> 2) << 4);
                A2[t][s][i] = (short)f2bf(W[OW2 + (16*t + ml)*64 + 32*s + k]);
            }
    #pragma unroll
    for (int i = 0; i < 8; ++i) {
        const int k = 4*g + (i & 3) + ((i >> 2) << 4);
        A3[i] = (short)f2bf(W[OW3 + ml*32 + k]);
        float v4 = 0.0f, v5 = 0.0f;
        if (ml < 8) v4 = (k < 16) ? W[OW4 + ml*16 + k] : ((k == 16) ? W[OB4 + ml] : 0.0f);
        if (ml < 2) v5 = (k <  8) ? W[OW5 + ml*8  + k] : ((k ==  8) ? W[OB5 + ml] : 0.0f);
        A4[i] = (short)f2bf(v4);
        A5[i] = (short)f2bf(v5);
    }
    f32x4 bias2[2], bias3;
    #pragma unroll
    for (int t = 0; t < 2; ++t)
        #pragma unroll
        for (int q = 0; q < 4; ++q)
            bias2[t][q] = W[OB2 + 16*t + 4*g + q];
    #pragma unroll
    for (int q = 0; q < 4; ++q)
        bias3[q] = W[OB3 + 4*g + q];

    // ---- pair loop: 2 independent tiles per iteration, grid-stride ----
    const int ntiles = (n + 15) >> 4;
    const int npairs = (ntiles + 1) >> 1;
    const int NW = gridDim.x * 4;
    int p = blockIdx.x * 4 + wv;
    if (p >= npairs) return;

    auto loadx = [&](int t, f32x4& xa, f32x4& xb) {
        int row = t*16 + ml;
        if (row >= n) row = n - 1;
        const float* rp = x + (size_t)row * 30;     // rows are 8B-aligned
        float2 a01 = *(const float2*)(rp + 4*g);
        float2 a23 = *(const float2*)(rp + 4*g + 2);
        xa[0] = a01.x; xa[1] = a01.y; xa[2] = a23.x; xa[3] = a23.y;
        if (g < 3) {
            float2 b01 = *(const float2*)(rp + 16 + 4*g);
            float2 b23 = *(const float2*)(rp + 18 + 4*g);
            xb[0] = b01.x; xb[1] = b01.y; xb[2] = b23.x; xb[3] = b23.y;
        } else {
            float2 b01 = *(const float2*)(rp + 28);
            xb[0] = b01.x; xb[1] = b01.y;
            xb[2] = 1.0f;   // k==30 slot multiplies the b1 column of W1
            xb[3] = 0.0f;   // k==31 pad
        }
    };

    f32x4 xa[2], xb[2];
    {
        const int t0 = 2*p;
        loadx(t0, xa[0], xb[0]);
        int t1 = t0 + 1; if (t1 >= ntiles) t1 = ntiles - 1;
        loadx(t1, xa[1], xb[1]);
    }

    const f32x4 zero = {0.0f, 0.0f, 0.0f, 0.0f};

    while (true) {
        const int np_ = p + NW;
        const bool have_next = (np_ < npairs);
        f32x4 nxa[2], nxb[2];
        if (have_next) {
            const int t0 = 2*np_;
            loadx(t0, nxa[0], nxb[0]);
            int t1 = t0 + 1; if (t1 >= ntiles) t1 = ntiles - 1;
            loadx(t1, nxa[1], nxb[1]);
        }

        // ---- layer 1: 30(+bias)->64 ----
        s16x8 B0[2];
        #pragma unroll
        for (int j = 0; j < 2; ++j) {
            u32x4 u0;
            u0.x = pkbf(xa[j][0], xa[j][1]); u0.y = pkbf(xa[j][2], xa[j][3]);
            u0.z = pkbf(xb[j][0], xb[j][1]); u0.w = pkbf(xb[j][2], xb[j][3]);
            B0[j] = __builtin_bit_cast(s16x8, u0);
        }
        f32x4 c1[2][4];
        #pragma unroll
        for (int t = 0; t < 4; ++t)
            #pragma unroll
            for (int j = 0; j < 2; ++j)
                c1[j][t] = MFMA(A1[t], B0[j], zero);

        // ---- layer 2: 64->32 (K = 2 steps) ----
        s16x8 B1[2][2];
        #pragma unroll
        for (int j = 0; j < 2; ++j)
            #pragma unroll
            for (int s = 0; s < 2; ++s) {
                u32x4 u;
                u.x = rp2(c1[j][2*s][0],     c1[j][2*s][1]);
                u.y = rp2(c1[j][2*s][2],     c1[j][2*s][3]);
                u.z = rp2(c1[j][2*s + 1][0], c1[j][2*s + 1][1]);
                u.w = rp2(c1[j][2*s + 1][2], c1[j][2*s + 1][3]);
                B1[j][s] = __builtin_bit_cast(s16x8, u);
            }
        f32x4 c2[2][2];
        #pragma unroll
        for (int t = 0; t < 2; ++t)
            #pragma unroll
            for (int j = 0; j < 2; ++j) {
                f32x4 a = bias2[t];
                #pragma unroll
                for (int s = 0; s < 2; ++s) a = MFMA(A2[t][s], B1[j][s], a);
                c2[j][t] = a;
            }

        // ---- layer 3: 32->16 ----
        f32x4 c3[2];
        #pragma unroll
        for (int j = 0; j < 2; ++j) {
            u32x4 u2;
            u2.x = rp2(c2[j][0][0], c2[j][0][1]);
            u2.y = rp2(c2[j][0][2], c2[j][0][3]);
            u2.z = rp2(c2[j][1][0], c2[j][1][1]);
            u2.w = rp2(c2[j][1][2], c2[j][1][3]);
            c3[j] = MFMA(A3, __builtin_bit_cast(s16x8, u2), bias3);
        }

        // ---- layer 4: 16(+bias)->8 ----
        f32x4 c4[2];
        #pragma unroll
        for (int j = 0; j < 2; ++j) {
            u32x4 u3;
            u3.x = rp2(c3[j][0], c3[j][1]);
            u3.y = rp2(c3[j][2], c3[j][3]);
            u3.z = (g == 0) ? 0x3F80u : 0u;   // k==16 slot = 1.0 (bias)
            u3.w = 0u;
            c4[j] = MFMA(A4, __builtin_bit_cast(s16x8, u3), zero);
        }

        // ---- layer 5: 8(+bias)->2 (no ReLU) ----
        f32x4 c5[2];
        #pragma unroll
        for (int j = 0; j < 2; ++j) {
            // c4 == 0 exactly for g >= 2 (A4 rows m>=8 are zero), so rp2 gives 0.
            u32x4 u4;
            u4.x = (g == 2) ? 0x3F80u : rp2(c4[j][0], c4[j][1]);  // k==8 slot = bias
            u4.y = (g == 2) ? 0u      : rp2(c4[j][2], c4[j][3]);
            u4.z = 0u; u4.w = 0u;
            c5[j] = MFMA(A5, __builtin_bit_cast(s16x8, u4), zero);
        }

        // ---- store ----
        #pragma unroll
        for (int j = 0; j < 2; ++j) {
            const int tj = 2*p + j;
            const int orow = tj*16 + lane;   // lanes 0..15: m=0 -> c5[0], m=1 -> c5[1]
            if (tj < ntiles && lane < 16 && orow < n) {
                float2 o; o.x = c5[j][0]; o.y = c5[j][1];
                *(float2*)(out + (size_t)orow * 2) = o;
            }
        }

        if (!have_next) break;
        #pragma unroll
        for (int j = 0; j < 2; ++j) { xa[j] = nxa[j]; xb[j] = nxb[j]; }
        p = np_;
    }
}

extern "C" void kernel_launch(void* const* d_in, const int* in_sizes, int n_in,
                              void* d_out, int out_size, void* d_ws, size_t ws_size,
                              hipStream_t stream) {
    const float* x  = (const float*)d_in[0];
    const float* w1 = (const float*)d_in[1];
    const float* b1 = (const float*)d_in[2];
    const float* w2 = (const float*)d_in[3];
    const float* b2 = (const float*)d_in[4];
    const float* w3 = (const float*)d_in[5];
    const float* b3 = (const float*)d_in[6];
    const float* w4 = (const float*)d_in[7];
    const float* b4 = (const float*)d_in[8];
    const float* w5 = (const float*)d_in[9];
    const float* b5 = (const float*)d_in[10];
    float* out = (float*)d_out;

    const int n = in_sizes[0] / 30;           // 1,000,000 rows
    const int ntiles = (n + 15) >> 4;         // 62,500
    const int npairs = (ntiles + 1) >> 1;     // 31,250
    int blocks = (npairs + 3) / 4;
    if (blocks > 2048) blocks = 2048;         // 8192 waves, ~3.8 pairs/wave

    mlp_mfma_kernel<<<blocks, 256, 0, stream>>>(
        x, w1, b1, w2, b2, w3, b3, w4, b4, w5, b5, out, n);
}

// Round 6
// 44.576 us; speedup vs baseline: 1.1468x; 1.1061x over previous
//
#include <hip/hip_runtime.h>

// 5-layer MLP 30->64->32->16->8->2 with ReLU, bf16 MFMA (16x16x32), batch tile N=16.
// Register-resident layer chain (k-slot map k = 4g+(i&3)+16*(i>>2); C/D layout
// m = 16t+4g+q, same lane group -> inter-layer repack is lane-local).
// Round-6 fixes vs round 5 (which failed correctness):
//  (1) staging uses ONLY HW-verified DMA widths: 3x gld16 (3072 B) + 3x gld4
//      (768 B) = exactly 3840 B per pair, linear (lane x size stride).
//  (2) 256 B pad of each slot zeroed once (row-31 g==3 overread reads 0 * 0
//      instead of uninitialized LDS -> no NaN path).
//  (3) vmcnt waits use guaranteed-minimum post-target counts (12/6/0),
//      independent of how many store instructions the compiler emits.

typedef float        f32x4 __attribute__((ext_vector_type(4)));
typedef unsigned int u32x4 __attribute__((ext_vector_type(4)));
typedef short        s16x8 __attribute__((ext_vector_type(8)));

static __device__ __forceinline__ unsigned short f2bf(float f) {
    return __builtin_bit_cast(unsigned short, (__bf16)f);
}
static __device__ __forceinline__ unsigned int pkbf(float a, float b) {
    return (unsigned int)f2bf(a) | ((unsigned int)f2bf(b) << 16);
}
static __device__ __forceinline__ unsigned int rp2(float a, float b) {
    return pkbf(fmaxf(a, 0.0f), fmaxf(b, 0.0f));
}

static __device__ __forceinline__ void gld16(const void* g, void* l) {
    __builtin_amdgcn_global_load_lds(
        (const __attribute__((address_space(1))) unsigned int*)g,
        (__attribute__((address_space(3))) unsigned int*)l, 16, 0, 0);
}
static __device__ __forceinline__ void gld4(const void* g, void* l) {
    __builtin_amdgcn_global_load_lds(
        (const __attribute__((address_space(1))) unsigned int*)g,
        (__attribute__((address_space(3))) unsigned int*)l, 4, 0, 0);
}

#define MFMA(A, B, C) __builtin_amdgcn_mfma_f32_16x16x32_bf16((A), (B), (C), 0, 0, 0)

// Per-wave LDS: 3 slots x 4096 B (pair = 32 rows x 120 B = 3840 B + 256 B pad).
#define SLOT_B 4096
#define NSLOT  3

__global__ __launch_bounds__(256) void mlp_mfma_kernel(
    const float* __restrict__ x,
    const float* __restrict__ w1, const float* __restrict__ b1,
    const float* __restrict__ w2, const float* __restrict__ b2,
    const float* __restrict__ w3, const float* __restrict__ b3,
    const float* __restrict__ w4, const float* __restrict__ b4,
    const float* __restrict__ w5, const float* __restrict__ b5,
    float* __restrict__ out, int n)
{
    __shared__ __attribute__((aligned(16))) unsigned char ldsX[4][NSLOT * SLOT_B];

    const int lane = threadIdx.x & 63;
    const int wv   = threadIdx.x >> 6;
    const int g    = lane >> 4;
    const int ml   = lane & 15;

    unsigned char* myL = &ldsX[wv][0];

    // ---- zero the pad region of each slot (NaN-proof the g==3 overread) ----
    #pragma unroll
    for (int s = 0; s < NSLOT; ++s)
        *(unsigned int*)(myL + s * SLOT_B + 3840 + lane * 4) = 0u;

    // ---- per-wave weight / bias fragment build ----
    s16x8 A1[4], A2[2][2], A3, A4, A5;
    #pragma unroll
    for (int t = 0; t < 4; ++t) {
        #pragma unroll
        for (int i = 0; i < 8; ++i) {
            const int k = 4*g + (i & 3) + ((i >> 2) << 4);
            const int m = 16*t + ml;
            float v = (k < 30) ? w1[m*30 + k] : 0.0f;   // k=30,31 zero (bias via acc)
            A1[t][i] = (short)f2bf(v);
        }
    }
    #pragma unroll
    for (int t = 0; t < 2; ++t)
        #pragma unroll
        for (int s = 0; s < 2; ++s)
            #pragma unroll
            for (int i = 0; i < 8; ++i) {
                const int k = 4*g + (i & 3) + ((i >> 2) << 4);
                A2[t][s][i] = (short)f2bf(w2[(16*t + ml)*64 + 32*s + k]);
            }
    #pragma unroll
    for (int i = 0; i < 8; ++i) {
        const int k = 4*g + (i & 3) + ((i >> 2) << 4);
        A3[i] = (short)f2bf(w3[ml*32 + k]);
        float v4 = 0.0f, v5 = 0.0f;
        if (ml < 8) v4 = (k < 16) ? w4[ml*16 + k] : ((k == 16) ? b4[ml] : 0.0f);
        if (ml < 2) v5 = (k <  8) ? w5[ml*8  + k] : ((k ==  8) ? b5[ml] : 0.0f);
        A4[i] = (short)f2bf(v4);
        A5[i] = (short)f2bf(v5);
    }
    f32x4 bias1[4], bias2[2], bias3;
    #pragma unroll
    for (int t = 0; t < 4; ++t)
        #pragma unroll
        for (int q = 0; q < 4; ++q)
            bias1[t][q] = b1[16*t + 4*g + q];
    #pragma unroll
    for (int t = 0; t < 2; ++t)
        #pragma unroll
        for (int q = 0; q < 4; ++q)
            bias2[t][q] = b2[16*t + 4*g + q];
    #pragma unroll
    for (int q = 0; q < 4; ++q)
        bias3[q] = b3[4*g + q];

    // ---- pair pipeline: 2 tiles (32 rows) per iteration, depth-2 prefetch ----
    const int ntiles = (n + 15) >> 4;
    const int npairs = (ntiles + 1) >> 1;
    const int NW = gridDim.x * 4;
    const int p0 = blockIdx.x * 4 + wv;
    if (p0 >= npairs) return;

    const size_t xbytes = (size_t)n * 120;

    auto issue = [&](int pr, int sl) {
        size_t gb = (size_t)pr * 3840;
        if (gb + 3840 > xbytes) gb = xbytes - 3840;   // clamp (n >= 32)
        const unsigned char* gp = (const unsigned char*)x + gb;
        unsigned char* lp = myL + sl * SLOT_B;
        gld16(gp +        (size_t)lane * 16, lp);
        gld16(gp + 1024 + (size_t)lane * 16, lp + 1024);
        gld16(gp + 2048 + (size_t)lane * 16, lp + 2048);
        gld4 (gp + 3072 + (size_t)lane * 4,  lp + 3072);
        gld4 (gp + 3328 + (size_t)lane * 4,  lp + 3328);
        gld4 (gp + 3584 + (size_t)lane * 4,  lp + 3584);
    };

    // prologue: fill the pipeline
    issue(p0, 0);
    if (p0 + NW < npairs) issue(p0 + NW, 1);

    const f32x4 zero = {0.0f, 0.0f, 0.0f, 0.0f};
    int slot = 0;

    for (int p = p0; p < npairs; p += NW) {
        const int pf = p + 2 * NW;
        if (pf < npairs) {
            int s2 = slot + 2; if (s2 >= NSLOT) s2 -= NSLOT;
            issue(pf, s2);
            // >=12 loads issued after pair p's 6 -> vmcnt(12) guarantees p landed.
            asm volatile("s_waitcnt vmcnt(12)" ::: "memory");
        } else if (p + NW < npairs) {
            asm volatile("s_waitcnt vmcnt(6)" ::: "memory");
        } else {
            asm volatile("s_waitcnt vmcnt(0)" ::: "memory");
        }

        // ---- build B0 for the 2 tiles of this pair ----
        s16x8 B0[2];
        const bool fullpair = ((p + 1) * 32 <= n);
        if (fullpair) {
            const float* L = (const float*)(myL + slot * SLOT_B);
            #pragma unroll
            for (int j = 0; j < 2; ++j) {
                const float* rp = L + (16*j + ml) * 30 + 4*g;
                float2 a01 = *(const float2*)(rp);
                float2 a23 = *(const float2*)(rp + 2);
                float2 b01 = *(const float2*)(rp + 16);   // g==3: floats 28,29 (real)
                float2 b23 = *(const float2*)(rp + 18);   // g==3: next-row/pad, x0 weights
                u32x4 u;
                u.x = pkbf(a01.x, a01.y); u.y = pkbf(a23.x, a23.y);
                u.z = pkbf(b01.x, b01.y); u.w = pkbf(b23.x, b23.y);
                B0[j] = __builtin_bit_cast(s16x8, u);
            }
        } else {
            // tail pair (n % 32 != 0): direct clamped global reads
            #pragma unroll
            for (int j = 0; j < 2; ++j) {
                int row = p*32 + 16*j + ml;
                if (row >= n) row = n - 1;
                const float* rp = x + (size_t)row * 30 + 4*g;
                float2 a01 = *(const float2*)(rp);
                float2 a23 = *(const float2*)(rp + 2);
                float2 b01 = *(const float2*)(rp + 16);
                float2 b23 = (g < 3) ? *(const float2*)(rp + 18) : make_float2(0.f, 0.f);
                u32x4 u;
                u.x = pkbf(a01.x, a01.y); u.y = pkbf(a23.x, a23.y);
                u.z = pkbf(b01.x, b01.y); u.w = pkbf(b23.x, b23.y);
                B0[j] = __builtin_bit_cast(s16x8, u);
            }
        }

        // ---- layer 1: 30->64 (bias in accumulator) ----
        f32x4 c1[2][4];
        #pragma unroll
        for (int t = 0; t < 4; ++t)
            #pragma unroll
            for (int j = 0; j < 2; ++j)
                c1[j][t] = MFMA(A1[t], B0[j], bias1[t]);

        // ---- layer 2: 64->32 (K = 2 steps) ----
        s16x8 B1[2][2];
        #pragma unroll
        for (int j = 0; j < 2; ++j)
            #pragma unroll
            for (int s = 0; s < 2; ++s) {
                u32x4 u;
                u.x = rp2(c1[j][2*s][0],     c1[j][2*s][1]);
                u.y = rp2(c1[j][2*s][2],     c1[j][2*s][3]);
                u.z = rp2(c1[j][2*s + 1][0], c1[j][2*s + 1][1]);
                u.w = rp2(c1[j][2*s + 1][2], c1[j][2*s + 1][3]);
                B1[j][s] = __builtin_bit_cast(s16x8, u);
            }
        f32x4 c2[2][2];
        #pragma unroll
        for (int t = 0; t < 2; ++t)
            #pragma unroll
            for (int j = 0; j < 2; ++j) {
                f32x4 a = bias2[t];
                #pragma unroll
                for (int s = 0; s < 2; ++s) a = MFMA(A2[t][s], B1[j][s], a);
                c2[j][t] = a;
            }

        // ---- layer 3: 32->16 ----
        f32x4 c3[2];
        #pragma unroll
        for (int j = 0; j < 2; ++j) {
            u32x4 u2;
            u2.x = rp2(c2[j][0][0], c2[j][0][1]);
            u2.y = rp2(c2[j][0][2], c2[j][0][3]);
            u2.z = rp2(c2[j][1][0], c2[j][1][1]);
            u2.w = rp2(c2[j][1][2], c2[j][1][3]);
            c3[j] = MFMA(A3, __builtin_bit_cast(s16x8, u2), bias3);
        }

        // ---- layer 4: 16(+bias)->8 ----
        f32x4 c4[2];
        #pragma unroll
        for (int j = 0; j < 2; ++j) {
            u32x4 u3;
            u3.x = rp2(c3[j][0], c3[j][1]);
            u3.y = rp2(c3[j][2], c3[j][3]);
            u3.z = (g == 0) ? 0x3F80u : 0u;   // k==16 slot = 1.0 (bias)
            u3.w = 0u;
            c4[j] = MFMA(A4, __builtin_bit_cast(s16x8, u3), zero);
        }

        // ---- layer 5: 8(+bias)->2 (no ReLU) ----
        f32x4 c5[2];
        #pragma unroll
        for (int j = 0; j < 2; ++j) {
            // c4 == 0 exactly for g >= 2 (A4 rows m>=8 are zero), so rp2 gives 0.
            u32x4 u4;
            u4.x = (g == 2) ? 0x3F80u : rp2(c4[j][0], c4[j][1]);  // k==8 slot = bias
            u4.y = (g == 2) ? 0u      : rp2(c4[j][2], c4[j][3]);
            u4.z = 0u; u4.w = 0u;
            c5[j] = MFMA(A5, __builtin_bit_cast(s16x8, u4), zero);
        }

        // ---- store ----
        #pragma unroll
        for (int j = 0; j < 2; ++j) {
            const int orow = (2*p + j)*16 + lane;   // lanes 0..15: m=0,1 -> c5[0],c5[1]
            if (lane < 16 && orow < n) {
                float2 o; o.x = c5[j][0]; o.y = c5[j][1];
                *(float2*)(out + (size_t)orow * 2) = o;
            }
        }

        slot = (slot + 1 == NSLOT) ? 0 : slot + 1;
    }
}

extern "C" void kernel_launch(void* const* d_in, const int* in_sizes, int n_in,
                              void* d_out, int out_size, void* d_ws, size_t ws_size,
                              hipStream_t stream) {
    const float* x  = (const float*)d_in[0];
    const float* w1 = (const float*)d_in[1];
    const float* b1 = (const float*)d_in[2];
    const float* w2 = (const float*)d_in[3];
    const float* b2 = (const float*)d_in[4];
    const float* w3 = (const float*)d_in[5];
    const float* b3 = (const float*)d_in[6];
    const float* w4 = (const float*)d_in[7];
    const float* b4 = (const float*)d_in[8];
    const float* w5 = (const float*)d_in[9];
    const float* b5 = (const float*)d_in[10];
    float* out = (float*)d_out;

    const int n = in_sizes[0] / 30;           // 1,000,000 rows
    const int ntiles = (n + 15) >> 4;         // 62,500
    const int npairs = (ntiles + 1) >> 1;     // 31,250
    // LDS 48 KB/block -> 3 blocks/CU -> 768 blocks fill the chip exactly.
    int blocks = (npairs + 3) / 4;
    if (blocks > 768) blocks = 768;           // 3072 waves, ~10 pairs/wave

    mlp_mfma_kernel<<<blocks, 256, 0, stream>>>(
        x, w1, b1, w2, b2, w3, b3, w4, b4, w5, b5, out, n);
}